// Round 1
// baseline (894.843 us; speedup 1.0000x reference)
//
#include <hip/hip_runtime.h>
#include <hip/hip_bf16.h>
#include <math.h>

#define B_ 2048
#define N_ 512
#define D_ 128
#define H_ 256

// ---------------- MLP kernel ----------------
// ls = sigmoid(relu(X@W1 + b1)@W2 + b2) - 0.5, X:[M,128], W1:[128,256], W2:[256]
// block: 256 thr (tx=t&31 over cols, ty=t>>5 over rows), tile 64 rows x 256 cols,
// per-thread 8 rows x 8 cols (cols tx*4..+3 and 128+tx*4..+3)
#define TM 64
#define KC 16

__global__ __launch_bounds__(256) void mlp_kernel(
    const float* __restrict__ X, const float* __restrict__ W1,
    const float* __restrict__ b1, const float* __restrict__ W2,
    const float* __restrict__ b2, float* __restrict__ ls)
{
    __shared__ float Xs[128 * 68];      // [k][r], stride 68 (16B-aligned rows, conflict-lite)
    __shared__ float Ws[KC * 256];      // [kk][c], flat copy of W1 chunk

    const int t  = threadIdx.x;
    const int tx = t & 31;
    const int ty = t >> 5;
    const size_t m0 = (size_t)blockIdx.x * TM;

    // stage X tile, transposed to [k][r]; global reads fully coalesced
    {
        const float4* Xg = (const float4*)(X + m0 * D_);
        #pragma unroll
        for (int i = 0; i < 8; ++i) {
            int f = t + i * 256;            // linear float4 index in 64x128 tile
            float4 v = Xg[f];
            int r  = f >> 5;                // row 0..63
            int k0 = (f & 31) << 2;         // k 0..124
            Xs[(k0 + 0) * 68 + r] = v.x;
            Xs[(k0 + 1) * 68 + r] = v.y;
            Xs[(k0 + 2) * 68 + r] = v.z;
            Xs[(k0 + 3) * 68 + r] = v.w;
        }
    }

    float acc[8][8];
    #pragma unroll
    for (int i = 0; i < 8; ++i)
        #pragma unroll
        for (int j = 0; j < 8; ++j) acc[i][j] = 0.f;

    for (int kc = 0; kc < D_ / KC; ++kc) {
        __syncthreads();
        {   // stage W1 chunk: [KC][256] row-major == flat copy
            const float4* Wg  = (const float4*)(W1 + (size_t)kc * KC * H_);
            float4* Wsv = (float4*)Ws;
            #pragma unroll
            for (int i = 0; i < (KC * H_ / 4) / 256; ++i)
                Wsv[t + i * 256] = Wg[t + i * 256];
        }
        __syncthreads();
        #pragma unroll 4
        for (int kk = 0; kk < KC; ++kk) {
            const int k = kc * KC + kk;
            float4 a0 = *(const float4*)&Xs[k * 68 + ty * 8];
            float4 a1 = *(const float4*)&Xs[k * 68 + ty * 8 + 4];
            float4 w0 = *(const float4*)&Ws[kk * 256 + tx * 4];
            float4 w1 = *(const float4*)&Ws[kk * 256 + 128 + tx * 4];
            float a[8] = {a0.x, a0.y, a0.z, a0.w, a1.x, a1.y, a1.z, a1.w};
            float w[8] = {w0.x, w0.y, w0.z, w0.w, w1.x, w1.y, w1.z, w1.w};
            #pragma unroll
            for (int i = 0; i < 8; ++i)
                #pragma unroll
                for (int j = 0; j < 8; ++j)
                    acc[i][j] += a[i] * w[j];
        }
    }

    // epilogue: h = relu(acc + b1), z = h @ W2 (+ b2), ls = sigmoid(z) - 0.5
    float zp[8];
    #pragma unroll
    for (int i = 0; i < 8; ++i) zp[i] = 0.f;
    #pragma unroll
    for (int j = 0; j < 8; ++j) {
        const int c = (j < 4) ? (tx * 4 + j) : (128 + tx * 4 + (j - 4));
        float bb = b1[c];
        float w2 = W2[c];
        #pragma unroll
        for (int i = 0; i < 8; ++i) {
            float h = acc[i][j] + bb;
            h = h > 0.f ? h : 0.f;
            zp[i] += h * w2;
        }
    }
    // reduce over the 32 tx lanes (lane bits 0..4)
    #pragma unroll
    for (int s = 1; s < 32; s <<= 1)
        #pragma unroll
        for (int i = 0; i < 8; ++i)
            zp[i] += __shfl_xor(zp[i], s, 64);
    if (tx == 0) {
        float b2v = b2[0];
        #pragma unroll
        for (int i = 0; i < 8; ++i) {
            float z  = zp[i] + b2v;
            float sg = 1.f / (1.f + expf(-z));
            ls[m0 + ty * 8 + i] = sg - 0.5f;
        }
    }
}

// ---------------- selection kernel ----------------
// one block per batch row; exact iterative argmax (ties -> lowest index, matching lax.top_k)
__global__ __launch_bounds__(256) void select_kernel(
    const float* __restrict__ ls, const float* __restrict__ spread,
    const float* __restrict__ vol, float* __restrict__ action,
    float* __restrict__ conf_out)
{
    const int b = blockIdx.x;
    const int t = threadIdx.x;
    __shared__ float sv[4];
    __shared__ int   si[4];
    __shared__ float s_bv;
    __shared__ int   s_bi;

    float rv[2], lsv[2];
    bool  univ[2] = {false, false};
    #pragma unroll
    for (int j = 0; j < 2; ++j) {
        int n = t + j * 256;
        float sp = spread[(size_t)b * N_ + n];
        float vo = vol[(size_t)b * N_ + n];
        bool valid = isfinite(sp) && (sp > 0.f);
        rv[j]  = valid ? (vo / (sp + 1e-8f)) : -INFINITY;
        lsv[j] = ls[(size_t)b * N_ + n];
    }

    bool allow_all = false;

    // ---- top-50 by ratio -> universe mask ----
    for (int it = 0; it < 50; ++it) {
        float v = rv[0]; int idx = t;
        if (rv[1] > v) { v = rv[1]; idx = t + 256; }
        #pragma unroll
        for (int s = 1; s < 64; s <<= 1) {
            float ov = __shfl_xor(v, s, 64);
            int   oi = __shfl_xor(idx, s, 64);
            if (ov > v || (ov == v && oi < idx)) { v = ov; idx = oi; }
        }
        if ((t & 63) == 0) { sv[t >> 6] = v; si[t >> 6] = idx; }
        __syncthreads();
        if (t == 0) {
            float bv = sv[0]; int bi = si[0];
            #pragma unroll
            for (int w = 1; w < 4; ++w)
                if (sv[w] > bv || (sv[w] == bv && si[w] < bi)) { bv = sv[w]; bi = si[w]; }
            s_bv = bv; s_bi = bi;
        }
        __syncthreads();
        float bv = s_bv; int bi = s_bi;
        if (it == 0 && bv == -INFINITY) allow_all = true;  // no valid spread in row
        if (t == (bi & 255)) { rv[bi >> 8] = -INFINITY; univ[bi >> 8] = true; }
    }

    // ---- top-10 of |ls| within universe ----
    float mv[2];
    bool  sel[2] = {false, false};
    #pragma unroll
    for (int j = 0; j < 2; ++j)
        mv[j] = (univ[j] || allow_all) ? fabsf(lsv[j]) : -INFINITY;

    float conf = 0.f, Z = 0.f;
    for (int it = 0; it < 10; ++it) {
        float v = mv[0]; int idx = t;
        if (mv[1] > v) { v = mv[1]; idx = t + 256; }
        #pragma unroll
        for (int s = 1; s < 64; s <<= 1) {
            float ov = __shfl_xor(v, s, 64);
            int   oi = __shfl_xor(idx, s, 64);
            if (ov > v || (ov == v && oi < idx)) { v = ov; idx = oi; }
        }
        if ((t & 63) == 0) { sv[t >> 6] = v; si[t >> 6] = idx; }
        __syncthreads();
        if (t == 0) {
            float bv = sv[0]; int bi = si[0];
            #pragma unroll
            for (int w = 1; w < 4; ++w)
                if (sv[w] > bv || (sv[w] == bv && si[w] < bi)) { bv = sv[w]; bi = si[w]; }
            s_bv = bv; s_bi = bi;
        }
        __syncthreads();
        float bv = s_bv; int bi = s_bi;
        if (it == 0) conf = bv;           // max of masked_abs
        Z += bv;                          // sum over selected |ls|
        if (t == (bi & 255)) { mv[bi >> 8] = -INFINITY; sel[bi >> 8] = true; }
    }

    conf = isfinite(conf) ? conf : 0.f;
    float scale = (conf >= 0.05f) ? (1.f / (Z + 1e-8f)) : 0.f;
    #pragma unroll
    for (int j = 0; j < 2; ++j) {
        int n = t + j * 256;
        action[(size_t)b * N_ + n] = sel[j] ? lsv[j] * scale : 0.f;
    }
    if (t == 0) conf_out[b] = conf;
}

extern "C" void kernel_launch(void* const* d_in, const int* in_sizes, int n_in,
                              void* d_out, int out_size, void* d_ws, size_t ws_size,
                              hipStream_t stream)
{
    const float* X  = (const float*)d_in[0];
    const float* sp = (const float*)d_in[1];
    const float* vo = (const float*)d_in[2];
    const float* W1 = (const float*)d_in[3];
    const float* b1 = (const float*)d_in[4];
    const float* W2 = (const float*)d_in[5];
    const float* b2 = (const float*)d_in[6];

    float* action = (float*)d_out;
    float* conf   = action + (size_t)B_ * N_;
    float* ls     = (float*)d_ws;   // B*N floats = 4 MB scratch

    hipLaunchKernelGGL(mlp_kernel, dim3((B_ * N_) / TM), dim3(256), 0, stream,
                       X, W1, b1, W2, b2, ls);
    hipLaunchKernelGGL(select_kernel, dim3(B_), dim3(256), 0, stream,
                       ls, sp, vo, action, conf);
}

// Round 2
// 651.562 us; speedup vs baseline: 1.3734x; 1.3734x over previous
//
#include <hip/hip_runtime.h>
#include <hip/hip_bf16.h>
#include <math.h>

#define B_ 2048
#define N_ 512
#define D_ 128
#define H_ 256
#define G0 3e-4f   // repair margin: ~300x the bf16x3 score error (~1e-6)

typedef __attribute__((ext_vector_type(8))) short bf16x8;
typedef __attribute__((ext_vector_type(4))) short short4v;
typedef __attribute__((ext_vector_type(4))) float f32x4;

__device__ __forceinline__ short f2bf(float x) {          // rne f32 -> bf16
    unsigned u = __float_as_uint(x);
    u = u + 0x7fffu + ((u >> 16) & 1u);
    return (short)(u >> 16);
}
__device__ __forceinline__ float bf2f(short h) {
    return __uint_as_float(((unsigned)(unsigned short)h) << 16);
}

// ---------------- W1 pre-pack: fragment-ordered bf16 hi/lo ----------------
// B-frag (16x16x32): lane l holds B[k = ks*32 + (l>>4)*8 + j][n = nf*16 + (l&15)]
// Wp[( (nf*4 + ks)*64 + l )*8 + j]
__global__ __launch_bounds__(256) void pack_w(const float* __restrict__ W1,
                                              short* __restrict__ WpH,
                                              short* __restrict__ WpL)
{
    int tid = blockIdx.x * 256 + threadIdx.x;   // 0..4095
    int l  = tid & 63;
    int ks = (tid >> 6) & 3;
    int nf = tid >> 8;
    int n  = nf * 16 + (l & 15);
    int kb = ks * 32 + ((l >> 4) << 3);
    bf16x8 hi, lo;
    #pragma unroll
    for (int j = 0; j < 8; ++j) {
        float w = W1[(size_t)(kb + j) * H_ + n];
        short h = f2bf(w);
        hi[j] = h;
        lo[j] = f2bf(w - bf2f(h));
    }
    *(bf16x8*)&WpH[(size_t)tid * 8] = hi;
    *(bf16x8*)&WpL[(size_t)tid * 8] = lo;
}

// ---------------- MLP via bf16x3 MFMA ----------------
// block: 256 thr (4 waves), BM=64 rows, BN=256 (full H). wave wn owns cols wn*64..+63.
// K=128 staged whole in LDS (hi/lo, XOR-swizzled). B-hi in registers, B-lo streamed from L2.
__global__ __launch_bounds__(256, 2) void mlp_mfma(
    const float* __restrict__ X, const short* __restrict__ WpH,
    const short* __restrict__ WpL, const float* __restrict__ b1,
    const float* __restrict__ W2, const float* __restrict__ b2,
    float* __restrict__ ls)
{
    __shared__ short Xh[64 * 128];
    __shared__ short Xl[64 * 128];
    __shared__ float zl[256];

    const int t    = threadIdx.x;
    const int lane = t & 63;
    const int wn   = t >> 6;
    const size_t m0 = (size_t)blockIdx.x * 64;

    // resident B-hi fragments (64 VGPR)
    bf16x8 Bhi[4][4];
    const bf16x8* WH = (const bf16x8*)WpH;
    const bf16x8* WL = (const bf16x8*)WpL;
    #pragma unroll
    for (int q = 0; q < 4; ++q)
        #pragma unroll
        for (int ks = 0; ks < 4; ++ks)
            Bhi[q][ks] = WH[((wn * 4 + q) * 4 + ks) * 64 + lane];

    // stage X tile -> bf16 hi/lo, swizzled [row][k]
    {
        const float4* Xg = (const float4*)(X + m0 * D_);
        #pragma unroll
        for (int i = 0; i < 8; ++i) {
            int f = t + i * 256;
            float4 v = Xg[f];
            int row = f >> 5, k0 = (f & 31) << 2;
            float xv[4] = {v.x, v.y, v.z, v.w};
            short4v hv, lv;
            #pragma unroll
            for (int j = 0; j < 4; ++j) {
                short h = f2bf(xv[j]);
                hv[j] = h;
                lv[j] = f2bf(xv[j] - bf2f(h));
            }
            int sidx = (row * 128 + k0) ^ ((row & 7) << 3);
            *(short4v*)&Xh[sidx] = hv;
            *(short4v*)&Xl[sidx] = lv;
        }
    }
    __syncthreads();

    f32x4 acc[4][4];
    #pragma unroll
    for (int mf = 0; mf < 4; ++mf)
        #pragma unroll
        for (int q = 0; q < 4; ++q)
            acc[mf][q] = (f32x4){0.f, 0.f, 0.f, 0.f};

    #pragma unroll
    for (int ks = 0; ks < 4; ++ks) {
        bf16x8 Blo[4];
        #pragma unroll
        for (int q = 0; q < 4; ++q)
            Blo[q] = WL[((wn * 4 + q) * 4 + ks) * 64 + lane];
        #pragma unroll
        for (int mf = 0; mf < 4; ++mf) {
            int r = mf * 16 + (lane & 15);
            int sidx = (r * 128 + ks * 32 + ((lane >> 4) << 3)) ^ ((r & 7) << 3);
            bf16x8 Ah = *(const bf16x8*)&Xh[sidx];
            bf16x8 Al = *(const bf16x8*)&Xl[sidx];
            #pragma unroll
            for (int q = 0; q < 4; ++q) {
                acc[mf][q] = __builtin_amdgcn_mfma_f32_16x16x32_bf16(Ah, Bhi[q][ks], acc[mf][q], 0, 0, 0);
                acc[mf][q] = __builtin_amdgcn_mfma_f32_16x16x32_bf16(Al, Bhi[q][ks], acc[mf][q], 0, 0, 0);
                acc[mf][q] = __builtin_amdgcn_mfma_f32_16x16x32_bf16(Ah, Blo[q],     acc[mf][q], 0, 0, 0);
            }
        }
    }

    // epilogue: h=relu(acc+b1); z=h@W2; reduce cols (16-lane groups, then cross-wave via LDS)
    float b1v[4], w2v[4];
    #pragma unroll
    for (int q = 0; q < 4; ++q) {
        int c = wn * 64 + q * 16 + (lane & 15);
        b1v[q] = b1[c];
        w2v[q] = W2[c];
    }
    #pragma unroll
    for (int mf = 0; mf < 4; ++mf) {
        #pragma unroll
        for (int i = 0; i < 4; ++i) {
            float zz = 0.f;
            #pragma unroll
            for (int q = 0; q < 4; ++q) {
                float h = acc[mf][q][i] + b1v[q];
                h = h > 0.f ? h : 0.f;
                zz += h * w2v[q];
            }
            zz += __shfl_xor(zz, 1, 64);
            zz += __shfl_xor(zz, 2, 64);
            zz += __shfl_xor(zz, 4, 64);
            zz += __shfl_xor(zz, 8, 64);
            if ((lane & 15) == 0) zl[wn * 64 + mf * 16 + ((lane >> 4) << 2) + i] = zz;
        }
    }
    __syncthreads();
    if (t < 64) {
        float z = zl[t] + zl[64 + t] + zl[128 + t] + zl[192 + t] + b2[0];
        ls[m0 + t] = 1.f / (1.f + expf(-z)) - 0.5f;
    }
}

// ---------------- block argmax helper (256 thr, lowest-index tiebreak) ----------------
__device__ __forceinline__ void block_argmax(float v, int idx, int t,
    float* sv, int* si, float* s_bv, int* s_bi)
{
    #pragma unroll
    for (int s = 1; s < 64; s <<= 1) {
        float ov = __shfl_xor(v, s, 64);
        int   oi = __shfl_xor(idx, s, 64);
        if (ov > v || (ov == v && oi < idx)) { v = ov; idx = oi; }
    }
    if ((t & 63) == 0) { sv[t >> 6] = v; si[t >> 6] = idx; }
    __syncthreads();
    if (t == 0) {
        float bv = sv[0]; int bi = si[0];
        #pragma unroll
        for (int w = 1; w < 4; ++w)
            if (sv[w] > bv || (sv[w] == bv && si[w] < bi)) { bv = sv[w]; bi = si[w]; }
        *s_bv = bv; *s_bi = bi;
    }
    __syncthreads();
}

// ---------------- selection (+ inline exact repair for boundary rows) ----------------
__global__ __launch_bounds__(256) void select_kernel(
    const float* __restrict__ ls, const float* __restrict__ spread,
    const float* __restrict__ vol, const float* __restrict__ X,
    const float* __restrict__ W1, const float* __restrict__ b1,
    const float* __restrict__ W2, const float* __restrict__ b2,
    float* __restrict__ action, float* __restrict__ conf_out)
{
    const int b = blockIdx.x;
    const int t = threadIdx.x;
    __shared__ float sv[4]; __shared__ int si[4];
    __shared__ float s_bv;  __shared__ int s_bi;
    __shared__ int   uidx[50];
    __shared__ float red[4];
    __shared__ float exv[512];
    __shared__ float selv[10]; __shared__ int seli[10];

    float rv[2], lsv[2];
    bool  univ[2] = {false, false};
    #pragma unroll
    for (int j = 0; j < 2; ++j) {
        int n = t + j * 256;
        float sp = spread[(size_t)b * N_ + n];
        float vo = vol[(size_t)b * N_ + n];
        bool valid = isfinite(sp) && (sp > 0.f);
        rv[j]  = valid ? (vo / (sp + 1e-8f)) : -INFINITY;
        lsv[j] = ls[(size_t)b * N_ + n];
    }

    bool allow_all = false;

    // ---- top-50 by ratio (exact) -> universe ----
    for (int it = 0; it < 50; ++it) {
        float v = rv[0]; int idx = t;
        if (rv[1] > v) { v = rv[1]; idx = t + 256; }
        block_argmax(v, idx, t, sv, si, &s_bv, &s_bi);
        float bv = s_bv; int bi = s_bi;
        if (it == 0 && bv == -INFINITY) allow_all = true;
        if (t == 0) uidx[it] = bi;
        if (t == (bi & 255)) { rv[bi >> 8] = -INFINITY; univ[bi >> 8] = true; }
    }

    // ---- fast top-10 of |ls| within universe ----
    float mv[2];
    bool  sel[2] = {false, false};
    #pragma unroll
    for (int j = 0; j < 2; ++j)
        mv[j] = (univ[j] || allow_all) ? fabsf(lsv[j]) : -INFINITY;

    float conf = 0.f, Z = 0.f, b10 = 0.f;
    for (int it = 0; it < 10; ++it) {
        float v = mv[0]; int idx = t;
        if (mv[1] > v) { v = mv[1]; idx = t + 256; }
        block_argmax(v, idx, t, sv, si, &s_bv, &s_bi);
        float bv = s_bv; int bi = s_bi;
        if (it == 0) conf = bv;
        if (it == 9) b10 = bv;
        Z += bv;
        if (t == (bi & 255)) { mv[bi >> 8] = -INFINITY; sel[bi >> 8] = true; }
    }
    // 11th max -> boundary gap
    {
        float v = mv[0]; int idx = t;
        if (mv[1] > v) { v = mv[1]; idx = t + 256; }
        block_argmax(v, idx, t, sv, si, &s_bv, &s_bi);
    }
    float b11 = s_bv;
    bool flag = (b10 - b11 < G0) || (fabsf(conf - 0.05f) < G0);

    if (!flag) {
        float cfin  = isfinite(conf) ? conf : 0.f;
        float scale = (cfin >= 0.05f) ? (1.f / (Z + 1e-8f)) : 0.f;
        #pragma unroll
        for (int j = 0; j < 2; ++j) {
            int n = t + j * 256;
            action[(size_t)b * N_ + n] = sel[j] ? lsv[j] * scale : 0.f;
        }
        if (t == 0) conf_out[b] = cfin;
    } else {
        // exact fp32 recompute of the universe assets, then exact selection
        int U = allow_all ? 512 : 50;
        for (int a = 0; a < U; ++a) {
            int asset = allow_all ? a : uidx[a];
            const float* xr = X + ((size_t)b * N_ + asset) * D_;
            float h = 0.f;
            #pragma unroll 4
            for (int k = 0; k < D_; ++k) h += xr[k] * W1[(size_t)k * H_ + t];
            h += b1[t];
            h = h > 0.f ? h : 0.f;
            float pz = h * W2[t];
            #pragma unroll
            for (int s = 1; s < 64; s <<= 1) pz += __shfl_xor(pz, s, 64);
            if ((t & 63) == 0) red[t >> 6] = pz;
            __syncthreads();
            if (t == 0) {
                float z = red[0] + red[1] + red[2] + red[3] + b2[0];
                exv[a] = 1.f / (1.f + expf(-z)) - 0.5f;
            }
            __syncthreads();
        }
        float v0 = (t < U)       ? fabsf(exv[t])       : -INFINITY;
        int   i0 = (t < U)       ? (allow_all ? t : uidx[t]) : (1 << 30);
        float v1 = (t + 256 < U) ? fabsf(exv[t + 256]) : -INFINITY;
        int   i1 = (t + 256 < U) ? (t + 256)           : (1 << 30);

        float confx = 0.f, Zx = 0.f;
        for (int it = 0; it < 10; ++it) {
            float v = v0; int idx = i0;
            if (v1 > v || (v1 == v && i1 < idx)) { v = v1; idx = i1; }
            block_argmax(v, idx, t, sv, si, &s_bv, &s_bi);
            float bv = s_bv; int bi = s_bi;
            if (it == 0) confx = bv;
            Zx += bv;
            if (i0 == bi) { selv[it] = exv[t];       v0 = -INFINITY; }
            else if (i1 == bi) { selv[it] = exv[t + 256]; v1 = -INFINITY; }
            if (t == 0) seli[it] = bi;
        }
        __syncthreads();
        float scale = (confx >= 0.05f) ? (1.f / (Zx + 1e-8f)) : 0.f;
        #pragma unroll
        for (int j = 0; j < 2; ++j) {
            int n = t + j * 256;
            float val = 0.f;
            #pragma unroll
            for (int it2 = 0; it2 < 10; ++it2)
                if (seli[it2] == n) val = selv[it2] * scale;
            action[(size_t)b * N_ + n] = val;
        }
        if (t == 0) conf_out[b] = confx;
    }
}

extern "C" void kernel_launch(void* const* d_in, const int* in_sizes, int n_in,
                              void* d_out, int out_size, void* d_ws, size_t ws_size,
                              hipStream_t stream)
{
    const float* X  = (const float*)d_in[0];
    const float* sp = (const float*)d_in[1];
    const float* vo = (const float*)d_in[2];
    const float* W1 = (const float*)d_in[3];
    const float* b1 = (const float*)d_in[4];
    const float* W2 = (const float*)d_in[5];
    const float* b2 = (const float*)d_in[6];

    float* action = (float*)d_out;
    float* conf   = action + (size_t)B_ * N_;

    float* ls = (float*)d_ws;                       // 4 MB
    size_t need = (size_t)B_ * N_ * 4 + 2 * (size_t)D_ * H_ * 2;
    short *WpH, *WpL;
    if (ws_size >= need) {
        WpH = (short*)((char*)d_ws + (size_t)B_ * N_ * 4);
        WpL = WpH + (size_t)D_ * H_;
    } else {
        // hedge: stash packed W in d_out tail; pack -> gemm -> select overwrites it last
        WpH = (short*)(action + (size_t)out_size - 2 * (size_t)D_ * H_ / 2);
        WpL = WpH + (size_t)D_ * H_;
    }

    hipLaunchKernelGGL(pack_w, dim3(16), dim3(256), 0, stream, W1, WpH, WpL);
    hipLaunchKernelGGL(mlp_mfma, dim3((B_ * N_) / 64), dim3(256), 0, stream,
                       X, WpH, WpL, b1, W2, b2, ls);
    hipLaunchKernelGGL(select_kernel, dim3(B_), dim3(256), 0, stream,
                       ls, sp, vo, X, W1, b1, W2, b2, action, conf);
}

// Round 3
// 417.446 us; speedup vs baseline: 2.1436x; 1.5608x over previous
//
#include <hip/hip_runtime.h>
#include <hip/hip_bf16.h>
#include <math.h>

#define B_ 2048
#define N_ 512
#define D_ 128
#define H_ 256
#define G0f 1e-4f   // repair margin: ~10x the bf16x3 max score error (~1e-5)

typedef __attribute__((ext_vector_type(8))) short bf16x8;
typedef __attribute__((ext_vector_type(4))) short short4v;
typedef __attribute__((ext_vector_type(4))) float f32x4;

__device__ __forceinline__ short f2bf(float x) {          // rne f32 -> bf16
    unsigned u = __float_as_uint(x);
    u = u + 0x7fffu + ((u >> 16) & 1u);
    return (short)(u >> 16);
}
__device__ __forceinline__ float bf2f(short h) {
    return __uint_as_float(((unsigned)(unsigned short)h) << 16);
}

// ---------------- W1 pre-pack: fragment-ordered bf16 hi/lo ----------------
__global__ __launch_bounds__(256) void pack_w(const float* __restrict__ W1,
                                              short* __restrict__ WpH,
                                              short* __restrict__ WpL)
{
    int tid = blockIdx.x * 256 + threadIdx.x;   // 0..4095
    int l  = tid & 63;
    int ks = (tid >> 6) & 3;
    int nf = tid >> 8;
    int n  = nf * 16 + (l & 15);
    int kb = ks * 32 + ((l >> 4) << 3);
    bf16x8 hi, lo;
    #pragma unroll
    for (int j = 0; j < 8; ++j) {
        float w = W1[(size_t)(kb + j) * H_ + n];
        short h = f2bf(w);
        hi[j] = h;
        lo[j] = f2bf(w - bf2f(h));
    }
    *(bf16x8*)&WpH[(size_t)tid * 8] = hi;
    *(bf16x8*)&WpL[(size_t)tid * 8] = lo;
}

// ---------------- MLP via bf16x3 MFMA (unchanged from round 2) ----------------
__global__ __launch_bounds__(256, 2) void mlp_mfma(
    const float* __restrict__ X, const short* __restrict__ WpH,
    const short* __restrict__ WpL, const float* __restrict__ b1,
    const float* __restrict__ W2, const float* __restrict__ b2,
    float* __restrict__ ls)
{
    __shared__ short Xh[64 * 128];
    __shared__ short Xl[64 * 128];
    __shared__ float zl[256];

    const int t    = threadIdx.x;
    const int lane = t & 63;
    const int wn   = t >> 6;
    const size_t m0 = (size_t)blockIdx.x * 64;

    bf16x8 Bhi[4][4];
    const bf16x8* WH = (const bf16x8*)WpH;
    const bf16x8* WL = (const bf16x8*)WpL;
    #pragma unroll
    for (int q = 0; q < 4; ++q)
        #pragma unroll
        for (int ks = 0; ks < 4; ++ks)
            Bhi[q][ks] = WH[((wn * 4 + q) * 4 + ks) * 64 + lane];

    {
        const float4* Xg = (const float4*)(X + m0 * D_);
        #pragma unroll
        for (int i = 0; i < 8; ++i) {
            int f = t + i * 256;
            float4 v = Xg[f];
            int row = f >> 5, k0 = (f & 31) << 2;
            float xv[4] = {v.x, v.y, v.z, v.w};
            short4v hv, lv;
            #pragma unroll
            for (int j = 0; j < 4; ++j) {
                short h = f2bf(xv[j]);
                hv[j] = h;
                lv[j] = f2bf(xv[j] - bf2f(h));
            }
            int sidx = (row * 128 + k0) ^ ((row & 7) << 3);
            *(short4v*)&Xh[sidx] = hv;
            *(short4v*)&Xl[sidx] = lv;
        }
    }
    __syncthreads();

    f32x4 acc[4][4];
    #pragma unroll
    for (int mf = 0; mf < 4; ++mf)
        #pragma unroll
        for (int q = 0; q < 4; ++q)
            acc[mf][q] = (f32x4){0.f, 0.f, 0.f, 0.f};

    #pragma unroll
    for (int ks = 0; ks < 4; ++ks) {
        bf16x8 Blo[4];
        #pragma unroll
        for (int q = 0; q < 4; ++q)
            Blo[q] = WL[((wn * 4 + q) * 4 + ks) * 64 + lane];
        #pragma unroll
        for (int mf = 0; mf < 4; ++mf) {
            int r = mf * 16 + (lane & 15);
            int sidx = (r * 128 + ks * 32 + ((lane >> 4) << 3)) ^ ((r & 7) << 3);
            bf16x8 Ah = *(const bf16x8*)&Xh[sidx];
            bf16x8 Al = *(const bf16x8*)&Xl[sidx];
            #pragma unroll
            for (int q = 0; q < 4; ++q) {
                acc[mf][q] = __builtin_amdgcn_mfma_f32_16x16x32_bf16(Ah, Bhi[q][ks], acc[mf][q], 0, 0, 0);
                acc[mf][q] = __builtin_amdgcn_mfma_f32_16x16x32_bf16(Al, Bhi[q][ks], acc[mf][q], 0, 0, 0);
                acc[mf][q] = __builtin_amdgcn_mfma_f32_16x16x32_bf16(Ah, Blo[q],     acc[mf][q], 0, 0, 0);
            }
        }
    }

    float b1v[4], w2v[4];
    #pragma unroll
    for (int q = 0; q < 4; ++q) {
        int c = wn * 64 + q * 16 + (lane & 15);
        b1v[q] = b1[c];
        w2v[q] = W2[c];
    }
    #pragma unroll
    for (int mf = 0; mf < 4; ++mf) {
        #pragma unroll
        for (int i = 0; i < 4; ++i) {
            float zz = 0.f;
            #pragma unroll
            for (int q = 0; q < 4; ++q) {
                float h = acc[mf][q][i] + b1v[q];
                h = h > 0.f ? h : 0.f;
                zz += h * w2v[q];
            }
            zz += __shfl_xor(zz, 1, 64);
            zz += __shfl_xor(zz, 2, 64);
            zz += __shfl_xor(zz, 4, 64);
            zz += __shfl_xor(zz, 8, 64);
            if ((lane & 15) == 0) zl[wn * 64 + mf * 16 + ((lane >> 4) << 2) + i] = zz;
        }
    }
    __syncthreads();
    if (t < 64) {
        float z = zl[t] + zl[64 + t] + zl[128 + t] + zl[192 + t] + b2[0];
        ls[m0 + t] = 1.f / (1.f + expf(-z)) - 0.5f;
    }
}

// ---------------- wave argmax over 8 register slots (n = lane + 64*j) ----------------
// lowest-global-index tiebreak, result broadcast to all lanes
__device__ __forceinline__ void wave_argmax8(const float (&mv)[8], int l,
                                             float& bv, int& bi)
{
    float v = mv[0]; int j = 0;
    #pragma unroll
    for (int s = 1; s < 8; ++s)
        if (mv[s] > v) { v = mv[s]; j = s; }   // strict > keeps lowest n in-lane
    int idx = l + (j << 6);
    #pragma unroll
    for (int s = 1; s < 64; s <<= 1) {
        float ov = __shfl_xor(v, s, 64);
        int   oi = __shfl_xor(idx, s, 64);
        if (ov > v || (ov == v && oi < idx)) { v = ov; idx = oi; }
    }
    bv = v; bi = idx;
}

// ---------------- selection: 1 wave/row fast path, block-coop exact repair ----------------
__global__ __launch_bounds__(256) void select_kernel(
    const float* __restrict__ ls, const float* __restrict__ spread,
    const float* __restrict__ vol, const float* __restrict__ X,
    const float* __restrict__ W1, const float* __restrict__ b1,
    const float* __restrict__ W2, const float* __restrict__ b2,
    float* __restrict__ action, float* __restrict__ conf_out)
{
    __shared__ int   s_uidx[4][50];
    __shared__ float s_xrow[50][128];
    __shared__ float s_mabs[512];
    __shared__ float s_val[512];
    __shared__ int   s_flag[4];
    __shared__ float s_cz[2];       // confx, Zx for current repair row

    const int t = threadIdx.x;
    const int l = t & 63;
    const int w = t >> 6;
    const int b = blockIdx.x * 4 + w;
    const size_t base = (size_t)b * N_;

    // ---------- fast path: wave-private, barrier-free ----------
    float rv[8], lsv[8], mv[8];
    #pragma unroll
    for (int j = 0; j < 8; ++j) {
        int n = l + (j << 6);
        float sp = spread[base + n];
        float vo = vol[base + n];
        bool valid = isfinite(sp) && (sp > 0.f);
        rv[j]  = valid ? (vo / (sp + 1e-8f)) : -INFINITY;
        lsv[j] = ls[base + n];
    }

    bool allow_all = false;
    unsigned umask = 0;
    for (int it = 0; it < 50; ++it) {
        float bv; int bi;
        wave_argmax8(rv, l, bv, bi);
        if (it == 0 && bv == -INFINITY) allow_all = true;
        if (l == 0) s_uidx[w][it] = bi;
        #pragma unroll
        for (int j = 0; j < 8; ++j)
            if (bi == l + (j << 6)) { rv[j] = -INFINITY; umask |= 1u << j; }
    }

    #pragma unroll
    for (int j = 0; j < 8; ++j)
        mv[j] = (allow_all || ((umask >> j) & 1)) ? fabsf(lsv[j]) : -INFINITY;

    float conf = 0.f, Z = 0.f, b10 = 0.f;
    unsigned smask = 0;
    for (int it = 0; it < 10; ++it) {
        float bv; int bi;
        wave_argmax8(mv, l, bv, bi);
        if (it == 0) conf = bv;
        if (it == 9) b10 = bv;
        Z += bv;
        #pragma unroll
        for (int j = 0; j < 8; ++j)
            if (bi == l + (j << 6)) { mv[j] = -INFINITY; smask |= 1u << j; }
    }
    float b11; { int bi; wave_argmax8(mv, l, b11, bi); }

    bool flag = (b10 - b11 < G0f) || (fabsf(conf - 0.05f) < G0f);

    if (!flag) {
        float cfin  = isfinite(conf) ? conf : 0.f;
        float scale = (cfin >= 0.05f) ? (1.f / (Z + 1e-8f)) : 0.f;
        #pragma unroll
        for (int j = 0; j < 8; ++j) {
            int n = l + (j << 6);
            action[base + n] = ((smask >> j) & 1) ? lsv[j] * scale : 0.f;
        }
        if (l == 0) conf_out[b] = cfin;
    }
    if (l == 0) s_flag[w] = (flag ? 1 : 0) | (allow_all ? 2 : 0);
    __syncthreads();

    // ---------- exact fp32 repair, block-cooperative ----------
    for (int r = 0; r < 4; ++r) {
        int fl = s_flag[r];
        if (!(fl & 1)) continue;
        bool allow = (fl & 2) != 0;
        int U = allow ? 512 : 50;
        int brow = blockIdx.x * 4 + r;
        size_t rbase = (size_t)brow * N_;

        // init exact-score arrays
        s_mabs[t] = -INFINITY; s_mabs[t + 256] = -INFINITY;
        s_val[t]  = 0.f;       s_val[t + 256]  = 0.f;

        // stage the 50 universe X rows (skip for allow_all: read global)
        if (!allow) {
            #pragma unroll
            for (int a0 = 0; a0 < 56; a0 += 8) {
                int a = a0 + (t >> 5);
                if (a < 50) {
                    int asset = s_uidx[r][a];
                    const float4* src = (const float4*)(X + (rbase + asset) * D_);
                    ((float4*)&s_xrow[a][0])[t & 31] = src[t & 31];
                }
            }
        }
        __syncthreads();

        // exact scores: wave w handles assets a = w, w+4, ... ; 4 cols/lane
        float4 b1v = *(const float4*)&b1[l * 4];
        float4 w2v = *(const float4*)&W2[l * 4];
        for (int a = w; a < U; a += 4) {
            int asset = allow ? a : s_uidx[r][a];
            float h0 = 0.f, h1 = 0.f, h2 = 0.f, h3 = 0.f;
            if (!allow) {
                #pragma unroll 8
                for (int k = 0; k < D_; ++k) {
                    float xk = s_xrow[a][k];
                    float4 wv = *(const float4*)&W1[(size_t)k * H_ + l * 4];
                    h0 += xk * wv.x; h1 += xk * wv.y; h2 += xk * wv.z; h3 += xk * wv.w;
                }
            } else {
                const float* xr = X + (rbase + asset) * D_;
                #pragma unroll 8
                for (int k = 0; k < D_; ++k) {
                    float xk = xr[k];
                    float4 wv = *(const float4*)&W1[(size_t)k * H_ + l * 4];
                    h0 += xk * wv.x; h1 += xk * wv.y; h2 += xk * wv.z; h3 += xk * wv.w;
                }
            }
            h0 += b1v.x; h1 += b1v.y; h2 += b1v.z; h3 += b1v.w;
            float zp = (h0 > 0.f ? h0 : 0.f) * w2v.x + (h1 > 0.f ? h1 : 0.f) * w2v.y
                     + (h2 > 0.f ? h2 : 0.f) * w2v.z + (h3 > 0.f ? h3 : 0.f) * w2v.w;
            #pragma unroll
            for (int s = 1; s < 64; s <<= 1) zp += __shfl_xor(zp, s, 64);
            if (l == 0) {
                float v = 1.f / (1.f + expf(-(zp + b2[0]))) - 0.5f;
                s_mabs[asset] = fabsf(v);
                s_val[asset]  = v;
            }
        }
        __syncthreads();

        // owner wave redoes exact top-10
        if (w == r) {
            float mv2[8], val2[8];
            #pragma unroll
            for (int j = 0; j < 8; ++j) {
                mv2[j]  = s_mabs[l + (j << 6)];
                val2[j] = s_val[l + (j << 6)];
            }
            float confx = 0.f, Zx = 0.f;
            unsigned sm2 = 0;
            for (int it = 0; it < 10; ++it) {
                float bv; int bi;
                wave_argmax8(mv2, l, bv, bi);
                if (it == 0) confx = bv;
                Zx += bv;
                #pragma unroll
                for (int j = 0; j < 8; ++j)
                    if (bi == l + (j << 6)) { mv2[j] = -INFINITY; sm2 |= 1u << j; }
            }
            confx = isfinite(confx) ? confx : 0.f;
            float scale = (confx >= 0.05f) ? (1.f / (Zx + 1e-8f)) : 0.f;
            #pragma unroll
            for (int j = 0; j < 8; ++j) {
                int n = l + (j << 6);
                action[rbase + n] = ((sm2 >> j) & 1) ? val2[j] * scale : 0.f;
            }
            if (l == 0) conf_out[brow] = confx;
        }
        __syncthreads();   // before LDS reuse by next flagged row
    }
}

extern "C" void kernel_launch(void* const* d_in, const int* in_sizes, int n_in,
                              void* d_out, int out_size, void* d_ws, size_t ws_size,
                              hipStream_t stream)
{
    const float* X  = (const float*)d_in[0];
    const float* sp = (const float*)d_in[1];
    const float* vo = (const float*)d_in[2];
    const float* W1 = (const float*)d_in[3];
    const float* b1 = (const float*)d_in[4];
    const float* W2 = (const float*)d_in[5];
    const float* b2 = (const float*)d_in[6];

    float* action = (float*)d_out;
    float* conf   = action + (size_t)B_ * N_;

    float* ls = (float*)d_ws;                       // 4 MB
    size_t need = (size_t)B_ * N_ * 4 + 2 * (size_t)D_ * H_ * 2;
    short *WpH, *WpL;
    if (ws_size >= need) {
        WpH = (short*)((char*)d_ws + (size_t)B_ * N_ * 4);
        WpL = WpH + (size_t)D_ * H_;
    } else {
        WpH = (short*)(action + (size_t)out_size - 2 * (size_t)D_ * H_ / 2);
        WpL = WpH + (size_t)D_ * H_;
    }

    hipLaunchKernelGGL(pack_w, dim3(16), dim3(256), 0, stream, W1, WpH, WpL);
    hipLaunchKernelGGL(mlp_mfma, dim3((B_ * N_) / 64), dim3(256), 0, stream,
                       X, WpH, WpL, b1, W2, b2, ls);
    hipLaunchKernelGGL(select_kernel, dim3(B_ / 4), dim3(256), 0, stream,
                       ls, sp, vo, X, W1, b1, W2, b2, action, conf);
}